// Round 1
// baseline (175.824 us; speedup 1.0000x reference)
//
#include <hip/hip_runtime.h>

typedef unsigned int u32;
typedef unsigned short u16;

// ---------------------------------------------------------------------------
// Prep: W_in [1024][768] f32 (row-major)  ->  Wt [768][1024] bf16 (row-major)
// so that a feature's 1024-wide column is contiguous (2 KB) for the gather.
// ---------------------------------------------------------------------------
__global__ __launch_bounds__(256) void prep_wt(const float* __restrict__ W_in,
                                               u16* __restrict__ Wt) {
    int idx = blockIdx.x * 256 + threadIdx.x;   // 0 .. 768*1024-1
    int f = idx >> 10;                          // feature 0..767
    int l = idx & 1023;                         // hidden unit 0..1023
    u32 u = __float_as_uint(W_in[l * 768 + f]);
    u32 r = u + 0x7fffu + ((u >> 16) & 1u);     // round-to-nearest-even bf16
    Wt[idx] = (u16)(r >> 16);
}

// ---------------------------------------------------------------------------
// Main: one wave (64 lanes) per batch row.
//   1. read x row (768 f32, 3x float4/lane, coalesced), find active features
//      via deterministic wave prefix-sum -> compact list in LDS
//   2. bucket = (popcount-1)>>2 known up front -> only ONE head needed
//   3. gather bf16 columns of Wt; lane owns h[lane*16 .. lane*16+15]
//   4. fused: h = clip(acc + b_in, 0, 1); dot with W_h[bucket]; + psqt; reduce
// ---------------------------------------------------------------------------
__global__ __launch_bounds__(256) void nnue_fwd(
    const float* __restrict__ x,       // [B][768]
    const u16*   __restrict__ Wt,      // [768][1024] bf16
    const float* __restrict__ b_in,    // [1024]
    const float* __restrict__ W_h,     // [8][1024]
    const float* __restrict__ b_h,     // [8]
    const float* __restrict__ W_psqt,  // [768]
    float* __restrict__ out,           // [B]
    int B) {
    const int wave = threadIdx.x >> 6;
    const int lane = threadIdx.x & 63;
    const int row  = (blockIdx.x << 2) | wave;
    const int rc   = row < B ? row : B - 1;   // clamped for tail safety

    __shared__ u16 lists[4][32];

    // ---- 1. load x row, classify nonzeros -------------------------------
    const float4* xr = (const float4*)(x + (size_t)rc * 768);
    float4 v0 = xr[lane];
    float4 v1 = xr[lane + 64];
    float4 v2 = xr[lane + 128];
    float xs[12] = {v0.x, v0.y, v0.z, v0.w,
                    v1.x, v1.y, v1.z, v1.w,
                    v2.x, v2.y, v2.z, v2.w};

    int tl = 0;
#pragma unroll
    for (int k = 0; k < 12; ++k) tl += (xs[k] != 0.0f);

    // inclusive prefix-sum over 64 lanes (deterministic order)
    int incl = tl;
#pragma unroll
    for (int d = 1; d < 64; d <<= 1) {
        int t = __shfl_up(incl, d);
        if (lane >= d) incl += t;
    }
    int off = incl - tl;
    int cnt = __shfl(incl, 63);                 // total actives, 1..32
    cnt = __builtin_amdgcn_readfirstlane(cnt);  // make it scalar

    int o = off;
#pragma unroll
    for (int k = 0; k < 12; ++k) {
        if (xs[k] != 0.0f) {
            int feat = ((k >> 2) << 8) + (lane << 2) + (k & 3);
            lists[wave][o++] = (u16)feat;
        }
    }
    __syncthreads();

    const int bucket = (cnt - 1) >> 2;          // 0..7

    // ---- 3. gather-accumulate columns of Wt -----------------------------
    float acc[16];
#pragma unroll
    for (int i = 0; i < 16; ++i) acc[i] = 0.0f;

    const u16* wl = Wt + (lane << 4);           // lane's 16-elem slice
    for (int i = 0; i < cnt; ++i) {
        int f = (int)lists[wave][i];
        f = __builtin_amdgcn_readfirstlane(f);  // wave-uniform -> SGPR base
        const uint4* p = (const uint4*)(wl + ((size_t)f << 10));
        uint4 a = p[0];
        uint4 b = p[1];
#define ACCP(r, uu)                                                    \
        { u32 _lo = (uu) << 16, _hi = (uu) & 0xffff0000u;              \
          acc[2*(r)]   += __uint_as_float(_lo);                        \
          acc[2*(r)+1] += __uint_as_float(_hi); }
        ACCP(0, a.x) ACCP(1, a.y) ACCP(2, a.z) ACCP(3, a.w)
        ACCP(4, b.x) ACCP(5, b.y) ACCP(6, b.z) ACCP(7, b.w)
#undef ACCP
    }

    // psqt partial: lanes 0..cnt-1 each grab one active feature's weight
    float psqt = 0.0f;
    if (lane < cnt) psqt = W_psqt[(int)lists[wave][lane]];

    // ---- 4. bias + clip + single-head dot + reduce ----------------------
    float dot = psqt;
    const float4* bi = (const float4*)(b_in + (lane << 4));
    const float4* wh = (const float4*)(W_h + (bucket << 10) + (lane << 4));
#pragma unroll
    for (int q = 0; q < 4; ++q) {
        float4 b4 = bi[q];
        float4 w4 = wh[q];
        float h;
        h = fminf(fmaxf(acc[4*q+0] + b4.x, 0.0f), 1.0f); dot += h * w4.x;
        h = fminf(fmaxf(acc[4*q+1] + b4.y, 0.0f), 1.0f); dot += h * w4.y;
        h = fminf(fmaxf(acc[4*q+2] + b4.z, 0.0f), 1.0f); dot += h * w4.z;
        h = fminf(fmaxf(acc[4*q+3] + b4.w, 0.0f), 1.0f); dot += h * w4.w;
    }
#pragma unroll
    for (int d = 32; d >= 1; d >>= 1) dot += __shfl_xor(dot, d);

    if (lane == 0 && row < B) out[row] = dot + b_h[bucket];
}

extern "C" void kernel_launch(void* const* d_in, const int* in_sizes, int n_in,
                              void* d_out, int out_size, void* d_ws, size_t ws_size,
                              hipStream_t stream) {
    const float* x      = (const float*)d_in[0];
    const float* W_in   = (const float*)d_in[1];
    const float* b_in   = (const float*)d_in[2];
    const float* W_h    = (const float*)d_in[3];
    const float* b_h    = (const float*)d_in[4];
    const float* W_psqt = (const float*)d_in[5];
    float* out = (float*)d_out;

    u16* Wt = (u16*)d_ws;   // needs 768*1024*2 = 1.5 MB of workspace

    prep_wt<<<(768 * 1024) / 256, 256, 0, stream>>>(W_in, Wt);

    int B = out_size;       // 65536
    int grid = (B + 3) / 4; // 4 rows (waves) per 256-thread block
    nnue_fwd<<<grid, 256, 0, stream>>>(x, Wt, b_in, W_h, b_h, W_psqt, out, B);
}